// Round 22
// baseline (169.003 us; speedup 1.0000x reference)
//
#include <hip/hip_runtime.h>

// Problem constants: N=8, T=256, H=8, KQ=128, V=32
#define N_ 8
#define T_ 256
#define H_ 8
#define KQ_ 128
#define V_ 32
#define QT_ 8
#define EPAD 9   // e_s leading dim: coprime to 32 banks

typedef float f32x4 __attribute__((ext_vector_type(4)));

// ---------------------------------------------------------------------------
// Phase 1 v5 (frozen from R12): tiled-GEMM projections, dst[n][h][d][t].
// grid: 256 = proj(2)*n(8)*h(8)*dh(2), 256 thr
// ---------------------------------------------------------------------------
__global__ __launch_bounds__(256) void proj_kernel(
    const float* __restrict__ query, const float* __restrict__ key,
    const float* __restrict__ Wq, const float* __restrict__ bq,
    const float* __restrict__ Wk, const float* __restrict__ bk,
    float* __restrict__ hqT, float* __restrict__ hkT)
{
  int b = blockIdx.x;
  int dh = b & 1;
  int h  = (b >> 1) & 7;
  int n  = (b >> 4) & 7;
  int proj = (b >> 7) & 1;
  const float* src  = proj ? key : query;
  const float* W    = proj ? Wk  : Wq;
  const float* bias = proj ? bk  : bq;
  float* dst        = proj ? hkT : hqT;
  int d0 = dh * 64;

  __shared__ float qs[256 * 36];
  __shared__ float ws[64 * 36];

  int tl   = threadIdx.x & 31;
  int dsub = threadIdx.x >> 5;
  const float* qsrc = src + (size_t)n * T_ * KQ_;
  const float* wsrc = W + (size_t)(h * KQ_ + d0) * KQ_;

  float acc[8][8];
#pragma unroll
  for (int it = 0; it < 8; ++it)
#pragma unroll
    for (int dd = 0; dd < 8; ++dd) acc[it][dd] = 0.f;

  for (int kc = 0; kc < 4; ++kc) {
    if (kc) __syncthreads();
    {
      int r = threadIdx.x >> 3, c4 = (threadIdx.x & 7) * 4;
#pragma unroll
      for (int rep = 0; rep < 8; ++rep) {
        int row = r + rep * 32;
        *(float4*)&qs[row * 36 + c4] =
            *(const float4*)&qsrc[(size_t)row * KQ_ + kc * 32 + c4];
      }
#pragma unroll
      for (int rep = 0; rep < 2; ++rep) {
        int row = r + rep * 32;
        *(float4*)&ws[row * 36 + c4] =
            *(const float4*)&wsrc[(size_t)row * KQ_ + kc * 32 + c4];
      }
    }
    __syncthreads();

#pragma unroll 2
    for (int j0 = 0; j0 < 32; j0 += 4) {
      float4 qv[8];
#pragma unroll
      for (int it = 0; it < 8; ++it)
        qv[it] = *(const float4*)&qs[(tl + 32 * it) * 36 + j0];
#pragma unroll
      for (int dd = 0; dd < 8; ++dd) {
        float4 w4 = *(const float4*)&ws[(dsub * 8 + dd) * 36 + j0];
#pragma unroll
        for (int it = 0; it < 8; ++it) {
          acc[it][dd] = fmaf(qv[it].x, w4.x, acc[it][dd]);
          acc[it][dd] = fmaf(qv[it].y, w4.y, acc[it][dd]);
          acc[it][dd] = fmaf(qv[it].z, w4.z, acc[it][dd]);
          acc[it][dd] = fmaf(qv[it].w, w4.w, acc[it][dd]);
        }
      }
    }
  }

#pragma unroll
  for (int dd = 0; dd < 8; ++dd) {
    int d = d0 + dsub * 8 + dd;
    float bb = bias[h * KQ_ + d];
    size_t base = (((size_t)n * H_ + h) * KQ_ + d) * T_;
#pragma unroll
    for (int it = 0; it < 8; ++it)
      dst[base + it * 32 + tl] = acc[it][dd] + bb;
  }
}

// ---------------------------------------------------------------------------
// Phase 2 FUSED v5 (R22): byte-identical compute to v4 (148us total, attnF
// ~113). Launched with 30KB DYNAMIC LDS -> 60.5KB/block -> 2 blocks/CU ->
// R=4 residency rounds: rounds 2..4 compute under rounds 1..3 store drain.
// Model: attnF = 38/R + 81 -> ~91 + occupancy penalty.
// grid: 2048 = n(8)*h(8)*qtile(32 of 8q), 256 threads.
// ---------------------------------------------------------------------------
extern __shared__ float dyn_pad[];   // unused; occupancy throttle only

__global__ __launch_bounds__(256) void attn_kernel(
    const float* __restrict__ hqT, const float* __restrict__ hkT,
    const int* __restrict__ mask, const float* __restrict__ value,
    float* __restrict__ p_out, float* __restrict__ out_ws)
{
  const float SCALE = 0.08838834764831845f;   // 1/sqrt(128)
  int b = blockIdx.x;
  int q0 = (b & 31) * QT_;
  int h  = (b >> 5) & 7;
  int n  = b >> 8;
  int t  = threadIdx.x;
  int row0 = (n * H_ + h) * T_ + q0;

  __shared__ float hq_s[KQ_ * 8];      // 4KB
  __shared__ float e_s[T_ * EPAD];     // 9.2KB
  __shared__ float wred[4 * 8];
  __shared__ float red_s[8 * 8 * 32];  // 8KB
  __shared__ float red_o[8 * 8 * 32];  // 8KB
  __shared__ float inv_s[8 * 32];      // 1KB

  const float* hqbase = hqT + ((size_t)n * H_ + h) * KQ_ * T_;
  const float* hkbase = hkT + ((size_t)n * H_ + h) * KQ_ * T_;

  {
    int qq = t & 7, j0 = t >> 3;
#pragma unroll
    for (int rep = 0; rep < 4; ++rep) {
      int j = j0 + rep * 32;
      hq_s[j * 8 + qq] = hqbase[(size_t)j * T_ + q0 + qq];
    }
  }
  __syncthreads();

  // scores: thread t = k
  float acc[8];
#pragma unroll
  for (int qq = 0; qq < 8; ++qq) acc[qq] = 0.f;
#pragma unroll 4
  for (int j = 0; j < KQ_; ++j) {
    float hk = hkbase[(size_t)j * T_ + t];
    float4 a0 = *(const float4*)&hq_s[j * 8];
    float4 a1 = *(const float4*)&hq_s[j * 8 + 4];
    acc[0] = fmaf(a0.x, hk, acc[0]);
    acc[1] = fmaf(a0.y, hk, acc[1]);
    acc[2] = fmaf(a0.z, hk, acc[2]);
    acc[3] = fmaf(a0.w, hk, acc[3]);
    acc[4] = fmaf(a1.x, hk, acc[4]);
    acc[5] = fmaf(a1.y, hk, acc[5]);
    acc[6] = fmaf(a1.z, hk, acc[6]);
    acc[7] = fmaf(a1.w, hk, acc[7]);
  }
#pragma unroll
  for (int qq = 0; qq < 8; ++qq) acc[qq] *= SCALE;

  // max over k: wave shfl reduce + cross-wave LDS
  float mloc[8];
#pragma unroll
  for (int qq = 0; qq < 8; ++qq) {
    float m = acc[qq];
    for (int off = 32; off >= 1; off >>= 1)
      m = fmaxf(m, __shfl_xor(m, off, 64));
    mloc[qq] = m;
  }
  if ((t & 63) == 0) {
    int w = t >> 6;
#pragma unroll
    for (int qq = 0; qq < 8; ++qq) wred[w * 8 + qq] = mloc[qq];
  }
  __syncthreads();
  {
    float ev[8];
#pragma unroll
    for (int qq = 0; qq < 8; ++qq) {
      float mx = fmaxf(fmaxf(wred[0*8+qq], wred[1*8+qq]),
                       fmaxf(wred[2*8+qq], wred[3*8+qq]));
      ev[qq] = __expf(acc[qq] - mx);
    }
    *(float4*)&e_s[t * EPAD]     = make_float4(ev[0], ev[1], ev[2], ev[3]);
    *(float4*)&e_s[t * EPAD + 4] = make_float4(ev[4], ev[5], ev[6], ev[7]);
  }
  __syncthreads();

  // denominators + PV: thread = (kg = t>>5, v = t&31)
  const int*   mrow = mask  + (size_t)n * T_ * V_;
  const float* vrow = value + (size_t)n * T_ * V_;
  int v = t & 31, kg = t >> 5;
  float s8[8], o8[8];
#pragma unroll
  for (int qq = 0; qq < 8; ++qq) { s8[qq] = 0.f; o8[qq] = 0.f; }
  for (int i = 0; i < 32; ++i) {
    int k = kg * 32 + i;
    float mf = (float)mrow[k * V_ + v];
    float vv = vrow[k * V_ + v];
    float4 e0 = *(const float4*)&e_s[k * EPAD];
    float4 e1 = *(const float4*)&e_s[k * EPAD + 4];
    float p;
    p = e0.x * mf; s8[0] += p; o8[0] = fmaf(p, vv, o8[0]);
    p = e0.y * mf; s8[1] += p; o8[1] = fmaf(p, vv, o8[1]);
    p = e0.z * mf; s8[2] += p; o8[2] = fmaf(p, vv, o8[2]);
    p = e0.w * mf; s8[3] += p; o8[3] = fmaf(p, vv, o8[3]);
    p = e1.x * mf; s8[4] += p; o8[4] = fmaf(p, vv, o8[4]);
    p = e1.y * mf; s8[5] += p; o8[5] = fmaf(p, vv, o8[5]);
    p = e1.z * mf; s8[6] += p; o8[6] = fmaf(p, vv, o8[6]);
    p = e1.w * mf; s8[7] += p; o8[7] = fmaf(p, vv, o8[7]);
  }
#pragma unroll
  for (int qq = 0; qq < 8; ++qq) {
    red_s[(kg * 8 + qq) * 32 + v] = s8[qq];
    red_o[(kg * 8 + qq) * 32 + v] = o8[qq];
  }
  __syncthreads();
  {
    int qq = t >> 5, v2 = t & 31;
    float s = 0.f, o = 0.f;
#pragma unroll
    for (int kg2 = 0; kg2 < 8; ++kg2) {
      s += red_s[(kg2 * 8 + qq) * 32 + v2];
      o += red_o[(kg2 * 8 + qq) * 32 + v2];
    }
    float inv = 1.0f / s;
    inv_s[qq * 32 + v2] = inv;
    out_ws[(((size_t)n * T_ + q0 + qq) * H_ + h) * V_ + v2] = o * inv;
  }
  __syncthreads();

  // direct p_attn streaming: 8 rows x 2048 f32x4 over 256 thr, NT coalesced
  {
    int v0 = (t & 7) * 4;
    f32x4 iv[8];
#pragma unroll
    for (int qq = 0; qq < 8; ++qq)
      iv[qq] = *(const f32x4*)&inv_s[qq * 32 + v0];
    f32x4* pbase = (f32x4*)p_out + (size_t)row0 * 2048;

#pragma unroll
    for (int rep = 0; rep < 8; ++rep) {
      int e4 = rep * 256 + t;
      int k  = rep * 32 + (t >> 3);
      const int4 m4 = *(const int4*)&mrow[k * V_ + v0];
      float fx = (float)m4.x, fy = (float)m4.y, fz = (float)m4.z, fw = (float)m4.w;
      f32x4 e0 = *(const f32x4*)&e_s[k * EPAD];
      f32x4 e1 = *(const f32x4*)&e_s[k * EPAD + 4];
      float e[8] = {e0.x, e0.y, e0.z, e0.w, e1.x, e1.y, e1.z, e1.w};
#pragma unroll
      for (int qq = 0; qq < 8; ++qq) {
        f32x4 pv;
        pv.x = e[qq] * fx * iv[qq].x;
        pv.y = e[qq] * fy * iv[qq].y;
        pv.z = e[qq] * fz * iv[qq].z;
        pv.w = e[qq] * fw * iv[qq].w;
        __builtin_nontemporal_store(pv, &pbase[(size_t)qq * 2048 + e4]);
      }
    }
  }
}

// ---------------------------------------------------------------------------
// Phase 3 v2 (frozen from R8)
// ---------------------------------------------------------------------------
__global__ __launch_bounds__(256) void outproj_kernel(
    const float* __restrict__ out_ws, const float* __restrict__ Wo,
    const float* __restrict__ bo, float* __restrict__ out_rep)
{
  __shared__ float wot[256 * 33];
  __shared__ float rows_s[4 * 256];
  __shared__ float red[4 * 32];
  int r0 = blockIdx.x * 4;
  for (int i = threadIdx.x; i < 32 * 256; i += 256) {
    int o = i >> 8, c = i & 255;
    wot[c * 33 + o] = Wo[i];
  }
  for (int i = threadIdx.x; i < 4 * 256; i += 256)
    rows_s[i] = out_ws[(size_t)r0 * 256 + i];
  __syncthreads();
  int o  = threadIdx.x & 31;
  int rr = (threadIdx.x >> 5) & 3;
  int kh = threadIdx.x >> 7;
  int cb = kh * 128;
  float acc = 0.f;
#pragma unroll 4
  for (int c = 0; c < 128; ++c)
    acc = fmaf(rows_s[rr * 256 + cb + c], wot[(cb + c) * 33 + o], acc);
  if (kh == 1) red[rr * 32 + o] = acc;
  __syncthreads();
  if (kh == 0)
    out_rep[(size_t)(r0 + rr) * 32 + o] = acc + red[rr * 32 + o] + bo[o];
}

// ---------------------------------------------------------------------------
extern "C" void kernel_launch(void* const* d_in, const int* in_sizes, int n_in,
                              void* d_out, int out_size, void* d_ws, size_t ws_size,
                              hipStream_t stream) {
  const float* value = (const float*)d_in[0];
  const float* key   = (const float*)d_in[1];
  const float* query = (const float*)d_in[2];
  const int*   mask  = (const int*)d_in[3];
  const float* Wq = (const float*)d_in[4];
  const float* bq = (const float*)d_in[5];
  const float* Wk = (const float*)d_in[6];
  const float* bk = (const float*)d_in[7];
  const float* Wo = (const float*)d_in[8];
  const float* bo = (const float*)d_in[9];

  float* out_rep = (float*)d_out;
  float* p_out   = (float*)d_out + (size_t)N_ * T_ * V_;

  float* hqT    = (float*)d_ws;
  float* hkT    = hqT + (size_t)N_ * H_ * KQ_ * T_;
  float* out_ws = hkT + (size_t)N_ * H_ * KQ_ * T_;

  hipLaunchKernelGGL(proj_kernel, dim3(256), dim3(256), 0, stream,
                     query, key, Wq, bq, Wk, bk, hqT, hkT);
  // 30KB dynamic LDS: occupancy throttle -> 2 blocks/CU -> 4 residency rounds
  hipLaunchKernelGGL(attn_kernel, dim3(2048), dim3(256), 30 * 1024, stream,
                     hqT, hkT, mask, value, p_out, out_ws);
  hipLaunchKernelGGL(outproj_kernel, dim3(512), dim3(256), 0, stream,
                     out_ws, Wo, bo, out_rep);
}

// Round 23
// 148.958 us; speedup vs baseline: 1.1346x; 1.1346x over previous
//
#include <hip/hip_runtime.h>

// Problem constants: N=8, T=256, H=8, KQ=128, V=32
#define N_ 8
#define T_ 256
#define H_ 8
#define KQ_ 128
#define V_ 32
#define QT_ 8
#define EPAD 9   // e_s leading dim: coprime to 32 banks

typedef float f32x4 __attribute__((ext_vector_type(4)));

// ---------------------------------------------------------------------------
// Phase 1 v5 (frozen from R12): tiled-GEMM projections, dst[n][h][d][t].
// grid: 256 = proj(2)*n(8)*h(8)*dh(2), 256 thr
// ---------------------------------------------------------------------------
__global__ __launch_bounds__(256) void proj_kernel(
    const float* __restrict__ query, const float* __restrict__ key,
    const float* __restrict__ Wq, const float* __restrict__ bq,
    const float* __restrict__ Wk, const float* __restrict__ bk,
    float* __restrict__ hqT, float* __restrict__ hkT)
{
  int b = blockIdx.x;
  int dh = b & 1;
  int h  = (b >> 1) & 7;
  int n  = (b >> 4) & 7;
  int proj = (b >> 7) & 1;
  const float* src  = proj ? key : query;
  const float* W    = proj ? Wk  : Wq;
  const float* bias = proj ? bk  : bq;
  float* dst        = proj ? hkT : hqT;
  int d0 = dh * 64;

  __shared__ float qs[256 * 36];
  __shared__ float ws[64 * 36];

  int tl   = threadIdx.x & 31;
  int dsub = threadIdx.x >> 5;
  const float* qsrc = src + (size_t)n * T_ * KQ_;
  const float* wsrc = W + (size_t)(h * KQ_ + d0) * KQ_;

  float acc[8][8];
#pragma unroll
  for (int it = 0; it < 8; ++it)
#pragma unroll
    for (int dd = 0; dd < 8; ++dd) acc[it][dd] = 0.f;

  for (int kc = 0; kc < 4; ++kc) {
    if (kc) __syncthreads();
    {
      int r = threadIdx.x >> 3, c4 = (threadIdx.x & 7) * 4;
#pragma unroll
      for (int rep = 0; rep < 8; ++rep) {
        int row = r + rep * 32;
        *(float4*)&qs[row * 36 + c4] =
            *(const float4*)&qsrc[(size_t)row * KQ_ + kc * 32 + c4];
      }
#pragma unroll
      for (int rep = 0; rep < 2; ++rep) {
        int row = r + rep * 32;
        *(float4*)&ws[row * 36 + c4] =
            *(const float4*)&wsrc[(size_t)row * KQ_ + kc * 32 + c4];
      }
    }
    __syncthreads();

#pragma unroll 2
    for (int j0 = 0; j0 < 32; j0 += 4) {
      float4 qv[8];
#pragma unroll
      for (int it = 0; it < 8; ++it)
        qv[it] = *(const float4*)&qs[(tl + 32 * it) * 36 + j0];
#pragma unroll
      for (int dd = 0; dd < 8; ++dd) {
        float4 w4 = *(const float4*)&ws[(dsub * 8 + dd) * 36 + j0];
#pragma unroll
        for (int it = 0; it < 8; ++it) {
          acc[it][dd] = fmaf(qv[it].x, w4.x, acc[it][dd]);
          acc[it][dd] = fmaf(qv[it].y, w4.y, acc[it][dd]);
          acc[it][dd] = fmaf(qv[it].z, w4.z, acc[it][dd]);
          acc[it][dd] = fmaf(qv[it].w, w4.w, acc[it][dd]);
        }
      }
    }
  }

#pragma unroll
  for (int dd = 0; dd < 8; ++dd) {
    int d = d0 + dsub * 8 + dd;
    float bb = bias[h * KQ_ + d];
    size_t base = (((size_t)n * H_ + h) * KQ_ + d) * T_;
#pragma unroll
    for (int it = 0; it < 8; ++it)
      dst[base + it * 32 + tl] = acc[it][dd] + bb;
  }
}

// ---------------------------------------------------------------------------
// Phase 2 FUSED v4 (REVERTED to R21 config — best measured: 148us total,
// attnF ~113). R22's 2-blocks/CU throttle regressed to 169: the NT store
// stream needs high wave count for store-issue MLP; 5 blocks/CU is the
// empirical optimum (8/CU=123, 5/CU=113, 2/CU=134).
// grid: 2048 = n(8)*h(8)*qtile(32 of 8q), 256 threads, 30.5KB static LDS.
// ---------------------------------------------------------------------------
__global__ __launch_bounds__(256) void attn_kernel(
    const float* __restrict__ hqT, const float* __restrict__ hkT,
    const int* __restrict__ mask, const float* __restrict__ value,
    float* __restrict__ p_out, float* __restrict__ out_ws)
{
  const float SCALE = 0.08838834764831845f;   // 1/sqrt(128)
  int b = blockIdx.x;
  int q0 = (b & 31) * QT_;
  int h  = (b >> 5) & 7;
  int n  = b >> 8;
  int t  = threadIdx.x;
  int row0 = (n * H_ + h) * T_ + q0;

  __shared__ float hq_s[KQ_ * 8];      // 4KB
  __shared__ float e_s[T_ * EPAD];     // 9.2KB
  __shared__ float wred[4 * 8];
  __shared__ float red_s[8 * 8 * 32];  // 8KB
  __shared__ float red_o[8 * 8 * 32];  // 8KB
  __shared__ float inv_s[8 * 32];      // 1KB

  const float* hqbase = hqT + ((size_t)n * H_ + h) * KQ_ * T_;
  const float* hkbase = hkT + ((size_t)n * H_ + h) * KQ_ * T_;

  {
    int qq = t & 7, j0 = t >> 3;
#pragma unroll
    for (int rep = 0; rep < 4; ++rep) {
      int j = j0 + rep * 32;
      hq_s[j * 8 + qq] = hqbase[(size_t)j * T_ + q0 + qq];
    }
  }
  __syncthreads();

  // scores: thread t = k
  float acc[8];
#pragma unroll
  for (int qq = 0; qq < 8; ++qq) acc[qq] = 0.f;
#pragma unroll 4
  for (int j = 0; j < KQ_; ++j) {
    float hk = hkbase[(size_t)j * T_ + t];
    float4 a0 = *(const float4*)&hq_s[j * 8];
    float4 a1 = *(const float4*)&hq_s[j * 8 + 4];
    acc[0] = fmaf(a0.x, hk, acc[0]);
    acc[1] = fmaf(a0.y, hk, acc[1]);
    acc[2] = fmaf(a0.z, hk, acc[2]);
    acc[3] = fmaf(a0.w, hk, acc[3]);
    acc[4] = fmaf(a1.x, hk, acc[4]);
    acc[5] = fmaf(a1.y, hk, acc[5]);
    acc[6] = fmaf(a1.z, hk, acc[6]);
    acc[7] = fmaf(a1.w, hk, acc[7]);
  }
#pragma unroll
  for (int qq = 0; qq < 8; ++qq) acc[qq] *= SCALE;

  // max over k: wave shfl reduce + cross-wave LDS
  float mloc[8];
#pragma unroll
  for (int qq = 0; qq < 8; ++qq) {
    float m = acc[qq];
    for (int off = 32; off >= 1; off >>= 1)
      m = fmaxf(m, __shfl_xor(m, off, 64));
    mloc[qq] = m;
  }
  if ((t & 63) == 0) {
    int w = t >> 6;
#pragma unroll
    for (int qq = 0; qq < 8; ++qq) wred[w * 8 + qq] = mloc[qq];
  }
  __syncthreads();
  {
    float ev[8];
#pragma unroll
    for (int qq = 0; qq < 8; ++qq) {
      float mx = fmaxf(fmaxf(wred[0*8+qq], wred[1*8+qq]),
                       fmaxf(wred[2*8+qq], wred[3*8+qq]));
      ev[qq] = __expf(acc[qq] - mx);
    }
    *(float4*)&e_s[t * EPAD]     = make_float4(ev[0], ev[1], ev[2], ev[3]);
    *(float4*)&e_s[t * EPAD + 4] = make_float4(ev[4], ev[5], ev[6], ev[7]);
  }
  __syncthreads();

  // denominators + PV: thread = (kg = t>>5, v = t&31)
  const int*   mrow = mask  + (size_t)n * T_ * V_;
  const float* vrow = value + (size_t)n * T_ * V_;
  int v = t & 31, kg = t >> 5;
  float s8[8], o8[8];
#pragma unroll
  for (int qq = 0; qq < 8; ++qq) { s8[qq] = 0.f; o8[qq] = 0.f; }
  for (int i = 0; i < 32; ++i) {
    int k = kg * 32 + i;
    float mf = (float)mrow[k * V_ + v];
    float vv = vrow[k * V_ + v];
    float4 e0 = *(const float4*)&e_s[k * EPAD];
    float4 e1 = *(const float4*)&e_s[k * EPAD + 4];
    float p;
    p = e0.x * mf; s8[0] += p; o8[0] = fmaf(p, vv, o8[0]);
    p = e0.y * mf; s8[1] += p; o8[1] = fmaf(p, vv, o8[1]);
    p = e0.z * mf; s8[2] += p; o8[2] = fmaf(p, vv, o8[2]);
    p = e0.w * mf; s8[3] += p; o8[3] = fmaf(p, vv, o8[3]);
    p = e1.x * mf; s8[4] += p; o8[4] = fmaf(p, vv, o8[4]);
    p = e1.y * mf; s8[5] += p; o8[5] = fmaf(p, vv, o8[5]);
    p = e1.z * mf; s8[6] += p; o8[6] = fmaf(p, vv, o8[6]);
    p = e1.w * mf; s8[7] += p; o8[7] = fmaf(p, vv, o8[7]);
  }
#pragma unroll
  for (int qq = 0; qq < 8; ++qq) {
    red_s[(kg * 8 + qq) * 32 + v] = s8[qq];
    red_o[(kg * 8 + qq) * 32 + v] = o8[qq];
  }
  __syncthreads();
  {
    int qq = t >> 5, v2 = t & 31;
    float s = 0.f, o = 0.f;
#pragma unroll
    for (int kg2 = 0; kg2 < 8; ++kg2) {
      s += red_s[(kg2 * 8 + qq) * 32 + v2];
      o += red_o[(kg2 * 8 + qq) * 32 + v2];
    }
    float inv = 1.0f / s;
    inv_s[qq * 32 + v2] = inv;
    out_ws[(((size_t)n * T_ + q0 + qq) * H_ + h) * V_ + v2] = o * inv;
  }
  __syncthreads();

  // direct p_attn streaming: 8 rows x 2048 f32x4 over 256 thr, NT coalesced
  {
    int v0 = (t & 7) * 4;
    f32x4 iv[8];
#pragma unroll
    for (int qq = 0; qq < 8; ++qq)
      iv[qq] = *(const f32x4*)&inv_s[qq * 32 + v0];
    f32x4* pbase = (f32x4*)p_out + (size_t)row0 * 2048;

#pragma unroll
    for (int rep = 0; rep < 8; ++rep) {
      int e4 = rep * 256 + t;
      int k  = rep * 32 + (t >> 3);
      const int4 m4 = *(const int4*)&mrow[k * V_ + v0];
      float fx = (float)m4.x, fy = (float)m4.y, fz = (float)m4.z, fw = (float)m4.w;
      f32x4 e0 = *(const f32x4*)&e_s[k * EPAD];
      f32x4 e1 = *(const f32x4*)&e_s[k * EPAD + 4];
      float e[8] = {e0.x, e0.y, e0.z, e0.w, e1.x, e1.y, e1.z, e1.w};
#pragma unroll
      for (int qq = 0; qq < 8; ++qq) {
        f32x4 pv;
        pv.x = e[qq] * fx * iv[qq].x;
        pv.y = e[qq] * fy * iv[qq].y;
        pv.z = e[qq] * fz * iv[qq].z;
        pv.w = e[qq] * fw * iv[qq].w;
        __builtin_nontemporal_store(pv, &pbase[(size_t)qq * 2048 + e4]);
      }
    }
  }
}

// ---------------------------------------------------------------------------
// Phase 3 v2 (frozen from R8)
// ---------------------------------------------------------------------------
__global__ __launch_bounds__(256) void outproj_kernel(
    const float* __restrict__ out_ws, const float* __restrict__ Wo,
    const float* __restrict__ bo, float* __restrict__ out_rep)
{
  __shared__ float wot[256 * 33];
  __shared__ float rows_s[4 * 256];
  __shared__ float red[4 * 32];
  int r0 = blockIdx.x * 4;
  for (int i = threadIdx.x; i < 32 * 256; i += 256) {
    int o = i >> 8, c = i & 255;
    wot[c * 33 + o] = Wo[i];
  }
  for (int i = threadIdx.x; i < 4 * 256; i += 256)
    rows_s[i] = out_ws[(size_t)r0 * 256 + i];
  __syncthreads();
  int o  = threadIdx.x & 31;
  int rr = (threadIdx.x >> 5) & 3;
  int kh = threadIdx.x >> 7;
  int cb = kh * 128;
  float acc = 0.f;
#pragma unroll 4
  for (int c = 0; c < 128; ++c)
    acc = fmaf(rows_s[rr * 256 + cb + c], wot[(cb + c) * 33 + o], acc);
  if (kh == 1) red[rr * 32 + o] = acc;
  __syncthreads();
  if (kh == 0)
    out_rep[(size_t)(r0 + rr) * 32 + o] = acc + red[rr * 32 + o] + bo[o];
}

// ---------------------------------------------------------------------------
extern "C" void kernel_launch(void* const* d_in, const int* in_sizes, int n_in,
                              void* d_out, int out_size, void* d_ws, size_t ws_size,
                              hipStream_t stream) {
  const float* value = (const float*)d_in[0];
  const float* key   = (const float*)d_in[1];
  const float* query = (const float*)d_in[2];
  const int*   mask  = (const int*)d_in[3];
  const float* Wq = (const float*)d_in[4];
  const float* bq = (const float*)d_in[5];
  const float* Wk = (const float*)d_in[6];
  const float* bk = (const float*)d_in[7];
  const float* Wo = (const float*)d_in[8];
  const float* bo = (const float*)d_in[9];

  float* out_rep = (float*)d_out;
  float* p_out   = (float*)d_out + (size_t)N_ * T_ * V_;

  float* hqT    = (float*)d_ws;
  float* hkT    = hqT + (size_t)N_ * H_ * KQ_ * T_;
  float* out_ws = hkT + (size_t)N_ * H_ * KQ_ * T_;

  hipLaunchKernelGGL(proj_kernel, dim3(256), dim3(256), 0, stream,
                     query, key, Wq, bq, Wk, bk, hqT, hkT);
  hipLaunchKernelGGL(attn_kernel, dim3(2048), dim3(256), 0, stream,
                     hqT, hkT, mask, value, p_out, out_ws);
  hipLaunchKernelGGL(outproj_kernel, dim3(512), dim3(256), 0, stream,
                     out_ws, Wo, bo, out_rep);
}